// Round 2
// baseline (422.452 us; speedup 1.0000x reference)
//
#include <hip/hip_runtime.h>

// units2indices: pack groups of num_bits bipolar {-1,+1} fp32 values into
// base-2 indices (first element of each group is the MSB).
//
// Memory-bound: 320 MB read + 32 MB write => ~56 us floor at 6.3 TB/s.
// R1 lesson: direct float4 loads at 80 B/lane stride ran at 0.84 TB/s
// (transaction-split + L1 thrash). Fix: coalesced global->LDS staging,
// then per-thread repack from LDS.
//
// Layout: block = 256 threads, 2 groups/thread -> tile = 5120 floats
// = 1280 float4 = 20 KB LDS. Global loads are unit-stride float4 per
// instruction; LDS reads are 5x ds_read_b128 at 80 B stride (8-way bank
// conflict, ~2.9x LDS penalty — irrelevant vs HBM ceiling).

__device__ __forceinline__ int bit_of(float x) {
    return x > 0.0f ? 1 : 0;   // +1.0 -> 1, -1.0 -> 0 ; exact
}

__global__ __launch_bounds__(256) void pack10_lds_kernel(
    const float4* __restrict__ in4, int2* __restrict__ out2,
    int num_pairs, long long total4)
{
    __shared__ float4 sh[1280];          // 20 KB
    const int tid = threadIdx.x;
    const long long base4 = (long long)blockIdx.x * 1280;

#pragma unroll
    for (int k = 0; k < 5; ++k) {
        const int idx = tid + k * 256;
        const long long g = base4 + idx;
        if (g < total4) sh[idx] = in4[g];   // coalesced: unit stride across lanes
    }
    __syncthreads();

    const int pair = blockIdx.x * 256 + tid;
    if (pair >= num_pairs) return;

    const float4* p = sh + tid * 5;      // 20 floats, 16B-aligned in LDS
    float4 v0 = p[0];
    float4 v1 = p[1];
    float4 v2 = p[2];
    float4 v3 = p[3];
    float4 v4 = p[4];

    int i0 = (bit_of(v0.x) << 9) | (bit_of(v0.y) << 8) | (bit_of(v0.z) << 7) | (bit_of(v0.w) << 6)
           | (bit_of(v1.x) << 5) | (bit_of(v1.y) << 4) | (bit_of(v1.z) << 3) | (bit_of(v1.w) << 2)
           | (bit_of(v2.x) << 1) |  bit_of(v2.y);
    int i1 = (bit_of(v2.z) << 9) | (bit_of(v2.w) << 8) | (bit_of(v3.x) << 7) | (bit_of(v3.y) << 6)
           | (bit_of(v3.z) << 5) | (bit_of(v3.w) << 4) | (bit_of(v4.x) << 3) | (bit_of(v4.y) << 2)
           | (bit_of(v4.z) << 1) |  bit_of(v4.w);

    out2[pair] = make_int2(i0, i1);
}

// Fallback for any other num_bits (correctness safety net; not the bench path).
__global__ __launch_bounds__(256) void pack_generic_kernel(
    const float* __restrict__ in, int* __restrict__ out, int n_groups, int num_bits)
{
    int t = blockIdx.x * blockDim.x + threadIdx.x;
    if (t >= n_groups) return;
    const float* g = in + (size_t)t * (size_t)num_bits;
    int idx = 0;
    for (int j = 0; j < num_bits; ++j)
        idx = (idx << 1) | (g[j] > 0.0f ? 1 : 0);
    out[t] = idx;
}

extern "C" void kernel_launch(void* const* d_in, const int* in_sizes, int n_in,
                              void* d_out, int out_size, void* d_ws, size_t ws_size,
                              hipStream_t stream)
{
    const float* in = (const float*)d_in[0];
    int* out = (int*)d_out;
    const int n = in_sizes[0];
    const int num_bits = (out_size > 0) ? (n / out_size) : 10;

    if (num_bits == 10 && (out_size & 1) == 0) {
        const int num_pairs = out_size >> 1;               // 4,000,000
        const long long total4 = (long long)num_pairs * 5; // float4 count
        const int block = 256;
        const int grid = (num_pairs + block - 1) / block;  // 15625
        pack10_lds_kernel<<<grid, block, 0, stream>>>(
            (const float4*)in, (int2*)out, num_pairs, total4);
    } else {
        const int block = 256;
        const int grid = (out_size + block - 1) / block;
        pack_generic_kernel<<<grid, block, 0, stream>>>(in, out, out_size, num_bits);
    }
}